// Round 1
// baseline (279.201 us; speedup 1.0000x reference)
//
#include <hip/hip_runtime.h>

// TPLoss: pred [B,N] fp32, labels [B,N] int32 (0/1) -> scalar fp32
//   p = sigmoid(pred); TP_b = sum(p*l); TN_b = sum((1-p)*(1-l))
//   out_b = TP_b / (1 - TP_b - TN_b); loss = -mean_b(out_b)
// Memory-bound: 268.4 MB read @ ~6.3 TB/s => ~43 us floor.

#define BDIM 256
#define ROWS 4096
#define COLS 8192

__global__ __launch_bounds__(BDIM) void tploss_main(
    const float* __restrict__ pred,
    const int* __restrict__ labels,
    float* __restrict__ acc)
{
    const int row = blockIdx.x;
    const int tid = threadIdx.x;

    const float4* p4 = (const float4*)(pred + (size_t)row * COLS);
    const int4*   l4 = (const int4*)(labels + (size_t)row * COLS);

    float tp = 0.0f, tn = 0.0f;

    // COLS / (BDIM*4) = 8192 / 1024 = 8 iterations; lane i reads 16B at
    // consecutive addresses -> fully coalesced dwordx4 loads.
#pragma unroll
    for (int it = 0; it < COLS / (BDIM * 4); ++it) {
        float4 p = p4[it * BDIM + tid];
        int4   l = l4[it * BDIM + tid];

        float s0 = 1.0f / (1.0f + __expf(-p.x));
        float s1 = 1.0f / (1.0f + __expf(-p.y));
        float s2 = 1.0f / (1.0f + __expf(-p.z));
        float s3 = 1.0f / (1.0f + __expf(-p.w));

        float f0 = (float)l.x, f1 = (float)l.y, f2 = (float)l.z, f3 = (float)l.w;

        tp = fmaf(s0, f0, tp);
        tp = fmaf(s1, f1, tp);
        tp = fmaf(s2, f2, tp);
        tp = fmaf(s3, f3, tp);

        tn = fmaf(1.0f - s0, 1.0f - f0, tn);
        tn = fmaf(1.0f - s1, 1.0f - f1, tn);
        tn = fmaf(1.0f - s2, 1.0f - f2, tn);
        tn = fmaf(1.0f - s3, 1.0f - f3, tn);
    }

    // wave-64 butterfly reduction
#pragma unroll
    for (int off = 32; off > 0; off >>= 1) {
        tp += __shfl_down(tp, off, 64);
        tn += __shfl_down(tn, off, 64);
    }

    __shared__ float stp[BDIM / 64];
    __shared__ float stn[BDIM / 64];
    const int wave = tid >> 6;
    const int lane = tid & 63;
    if (lane == 0) { stp[wave] = tp; stn[wave] = tn; }
    __syncthreads();

    if (tid == 0) {
        float TP = stp[0] + stp[1] + stp[2] + stp[3];
        float TN = stn[0] + stn[1] + stn[2] + stn[3];
        float out = TP / (1.0f - TP - TN);
        atomicAdd(acc, out);  // device-scope by default on CDNA
    }
}

__global__ void tploss_final(const float* __restrict__ acc, float* __restrict__ out) {
    out[0] = -acc[0] * (1.0f / (float)ROWS);
}

extern "C" void kernel_launch(void* const* d_in, const int* in_sizes, int n_in,
                              void* d_out, int out_size, void* d_ws, size_t ws_size,
                              hipStream_t stream) {
    const float* pred   = (const float*)d_in[0];
    const int*   labels = (const int*)d_in[1];
    float* acc = (float*)d_ws;   // 4 bytes of scratch: the row-loss accumulator

    // d_ws is poisoned 0xAA before every timed launch -> zero it on-stream
    // (async memset is graph-capture safe; harness itself uses it).
    hipMemsetAsync(acc, 0, sizeof(float), stream);

    tploss_main<<<ROWS, BDIM, 0, stream>>>(pred, labels, acc);
    tploss_final<<<1, 1, 0, stream>>>(acc, (float*)d_out);
}

// Round 2
// 272.018 us; speedup vs baseline: 1.0264x; 1.0264x over previous
//
#include <hip/hip_runtime.h>

// TPLoss: pred [B,N] fp32, labels [B,N] int32 (0/1) -> scalar fp32
//   s = sigmoid(pred); TP_b = sum(s*l); TN_b = sum((1-s)(1-l)) = N - Sp - Sl + TP
//   denom_b = 1 - TP - TN = 1 - N + Sp + Sl - 2*TP
//   loss = -mean_b(TP_b / denom_b)
//
// R1 lesson: compiler allocated 28 VGPRs -> 1 load-pair in flight -> latency
// bound (101 us, 16% HBM). Fix: explicit register-array preload of ALL
// 16 dwordx4 loads per thread before compute (MLP >> latency-BW product).

#define BDIM 256
#define ROWS 4096
#define COLS 8192
#define ITERS (COLS / (BDIM * 4))   // 8 float4's per thread per row

__global__ __launch_bounds__(BDIM) void tploss_rows(
    const float* __restrict__ pred,
    const int* __restrict__ labels,
    float* __restrict__ row_out)
{
    const int row = blockIdx.x;
    const int tid = threadIdx.x;

    const float4* p4 = (const float4*)(pred + (size_t)row * COLS);
    const int4*   l4 = (const int4*)(labels + (size_t)row * COLS);

    // Issue all 16 loads before touching any result: 16 KB in flight per
    // wave. Register arrays with constant indices -> pure VGPRs (~80).
    float4 pv[ITERS];
    int4   lv[ITERS];
#pragma unroll
    for (int i = 0; i < ITERS; ++i) pv[i] = p4[i * BDIM + tid];
#pragma unroll
    for (int i = 0; i < ITERS; ++i) lv[i] = l4[i * BDIM + tid];

    float sp = 0.0f;   // sum of sigmoids
    float tp = 0.0f;   // sum of s*l
    int   sl = 0;      // sum of labels (exact int)

#pragma unroll
    for (int i = 0; i < ITERS; ++i) {
        float s0 = 1.0f / (1.0f + __expf(-pv[i].x));
        float s1 = 1.0f / (1.0f + __expf(-pv[i].y));
        float s2 = 1.0f / (1.0f + __expf(-pv[i].z));
        float s3 = 1.0f / (1.0f + __expf(-pv[i].w));

        sp += (s0 + s1) + (s2 + s3);
        tp = fmaf(s0, (float)lv[i].x, tp);
        tp = fmaf(s1, (float)lv[i].y, tp);
        tp = fmaf(s2, (float)lv[i].z, tp);
        tp = fmaf(s3, (float)lv[i].w, tp);
        sl += lv[i].x + lv[i].y + lv[i].z + lv[i].w;
    }

    float slf = (float)sl;

    // wave-64 butterfly reduction of (sp, tp, slf)
#pragma unroll
    for (int off = 32; off > 0; off >>= 1) {
        sp  += __shfl_down(sp,  off, 64);
        tp  += __shfl_down(tp,  off, 64);
        slf += __shfl_down(slf, off, 64);
    }

    __shared__ float ssp[BDIM / 64], stp[BDIM / 64], ssl[BDIM / 64];
    const int wave = tid >> 6;
    const int lane = tid & 63;
    if (lane == 0) { ssp[wave] = sp; stp[wave] = tp; ssl[wave] = slf; }
    __syncthreads();

    if (tid == 0) {
        float SP = (ssp[0] + ssp[1]) + (ssp[2] + ssp[3]);
        float TP = (stp[0] + stp[1]) + (stp[2] + stp[3]);
        float SL = (ssl[0] + ssl[1]) + (ssl[2] + ssl[3]);
        float denom = 1.0f - (float)COLS + SP + SL - 2.0f * TP;
        row_out[row] = TP / denom;   // no atomics: one plain store per row
    }
}

__global__ __launch_bounds__(BDIM) void tploss_reduce(
    const float* __restrict__ row_out,
    float* __restrict__ out)
{
    const int tid = threadIdx.x;
    float s = 0.0f;
#pragma unroll
    for (int i = 0; i < ROWS / BDIM; ++i)
        s += row_out[i * BDIM + tid];

#pragma unroll
    for (int off = 32; off > 0; off >>= 1)
        s += __shfl_down(s, off, 64);

    __shared__ float sw[BDIM / 64];
    const int wave = tid >> 6;
    const int lane = tid & 63;
    if (lane == 0) sw[wave] = s;
    __syncthreads();

    if (tid == 0) {
        float tot = (sw[0] + sw[1]) + (sw[2] + sw[3]);
        out[0] = -tot * (1.0f / (float)ROWS);
    }
}

extern "C" void kernel_launch(void* const* d_in, const int* in_sizes, int n_in,
                              void* d_out, int out_size, void* d_ws, size_t ws_size,
                              hipStream_t stream) {
    const float* pred   = (const float*)d_in[0];
    const int*   labels = (const int*)d_in[1];
    float* row_out = (float*)d_ws;   // 4096 floats = 16 KB scratch; every
                                     // element written each call, no memset.

    tploss_rows<<<ROWS, BDIM, 0, stream>>>(pred, labels, row_out);
    tploss_reduce<<<1, BDIM, 0, stream>>>(row_out, (float*)d_out);
}